// Round 1
// baseline (1606.593 us; speedup 1.0000x reference)
//
#include <hip/hip_runtime.h>
#include <math.h>

#define H 128
#define NCLS 10
#define EPS 1e-5f
#define BN_BETA 1e-4f

// ---------------- column stats (sum, sumsq) over [N,128] ----------------
__global__ __launch_bounds__(256) void colstats_kernel(
    const float* __restrict__ X, int N,
    float* __restrict__ sum, float* __restrict__ sumsq) {
  int col = threadIdx.x & (H - 1);
  int sub = threadIdx.x >> 7;  // 0..1
  float s = 0.f, s2 = 0.f;
  for (int r = blockIdx.x * 2 + sub; r < N; r += gridDim.x * 2) {
    float v = X[(size_t)r * H + col];
    s += v; s2 += v * v;
  }
  __shared__ float ls[H], ls2[H];
  if (sub == 0) { ls[col] = s; ls2[col] = s2; }
  __syncthreads();
  if (sub == 1) {
    atomicAdd(&sum[col], ls[col] + s);
    atomicAdd(&sumsq[col], ls2[col] + s2);
  }
}

// ---------------- fold BN into weights: Wout[f][k]=s_f*W[f][k], c[k]=bias+sum_f(beta-mu_f*s_f)W[f][k]
__global__ __launch_bounds__(128) void fold_kernel(
    const float* __restrict__ W, const float* __restrict__ bias,
    const float* __restrict__ sum, const float* __restrict__ sumsq,
    float invN, int Kout,
    float* __restrict__ Wout, float* __restrict__ cout_) {
  int k = blockIdx.x;    // 0..Kout-1
  int f = threadIdx.x;   // 0..127
  float mu = sum[f] * invN;
  float var = sumsq[f] * invN - mu * mu;
  float s = 1.0f / sqrtf(fmaxf(var, 0.f) + EPS);
  float w = W[(size_t)f * Kout + k];
  Wout[(size_t)f * Kout + k] = s * w;
  __shared__ float red[H];
  red[f] = (BN_BETA - mu * s) * w;
  __syncthreads();
  for (int o = 64; o > 0; o >>= 1) {
    if (f < o) red[f] += red[f + o];
    __syncthreads();
  }
  if (f == 0) cout_[k] = red[0] + (bias ? bias[k] : 0.f);
}

// ---------------- GEMM [N,128] @ [128,128] + bias (+relu) ----------------
#define BM 64
__global__ __launch_bounds__(256) void gemm_kernel(
    const float* __restrict__ A, const float* __restrict__ B,
    const float* __restrict__ bias, float* __restrict__ Cmat,
    int N, int relu) {
  __shared__ float As[8][BM];   // [kk][row]
  __shared__ float Bs[8][H];    // [kk][col]
  int tid = threadIdx.x;
  int tc = tid & 15, tr = tid >> 4;  // tr 0..15
  int row0 = blockIdx.x * BM;
  float acc[4][8];
#pragma unroll
  for (int i = 0; i < 4; i++)
#pragma unroll
    for (int j = 0; j < 8; j++) acc[i][j] = 0.f;

  int la_row = tid >> 2;        // 0..63
  int la_k = (tid & 3) * 2;     // 0,2,4,6
  int lb_k = tid >> 5;          // 0..7
  int lb_col = (tid & 31) * 4;  // 0..124

  for (int k0 = 0; k0 < H; k0 += 8) {
    int gr = row0 + la_row;
    float2 av = make_float2(0.f, 0.f);
    if (gr < N) av = *(const float2*)&A[(size_t)gr * H + k0 + la_k];
    As[la_k][la_row] = av.x;
    As[la_k + 1][la_row] = av.y;
    float4 bv = *(const float4*)&B[(size_t)(k0 + lb_k) * H + lb_col];
    *(float4*)&Bs[lb_k][lb_col] = bv;
    __syncthreads();
#pragma unroll
    for (int kk = 0; kk < 8; ++kk) {
      float4 a4 = *(const float4*)&As[kk][tr * 4];
      float4 b0 = *(const float4*)&Bs[kk][tc * 4];
      float4 b1 = *(const float4*)&Bs[kk][64 + tc * 4];
      float a[4] = {a4.x, a4.y, a4.z, a4.w};
      float b[8] = {b0.x, b0.y, b0.z, b0.w, b1.x, b1.y, b1.z, b1.w};
#pragma unroll
      for (int i = 0; i < 4; i++)
#pragma unroll
        for (int j = 0; j < 8; j++) acc[i][j] += a[i] * b[j];
    }
    __syncthreads();
  }
#pragma unroll
  for (int i = 0; i < 4; i++) {
    int r = row0 + tr * 4 + i;
    if (r < N) {
#pragma unroll
      for (int jb = 0; jb < 2; jb++) {
        int c0 = jb * 64 + tc * 4;
        float4 o;
        o.x = acc[i][jb * 4 + 0] + bias[c0 + 0];
        o.y = acc[i][jb * 4 + 1] + bias[c0 + 1];
        o.z = acc[i][jb * 4 + 2] + bias[c0 + 2];
        o.w = acc[i][jb * 4 + 3] + bias[c0 + 3];
        if (relu) {
          o.x = fmaxf(o.x, 0.f); o.y = fmaxf(o.y, 0.f);
          o.z = fmaxf(o.z, 0.f); o.w = fmaxf(o.w, 0.f);
        }
        *(float4*)&Cmat[(size_t)r * H + c0] = o;
      }
    }
  }
}

// ---------------- CSR build ----------------
__global__ __launch_bounds__(256) void hist_kernel(
    const int* __restrict__ row, const int* __restrict__ col, int E,
    int* __restrict__ cnt, float* __restrict__ deg) {
  int e = blockIdx.x * 256 + threadIdx.x;
  if (e < E) {
    atomicAdd(&cnt[col[e]], 1);
    atomicAdd(&deg[row[e]], 1.0f);
  }
}

__global__ __launch_bounds__(256) void scanA_kernel(const int* __restrict__ cnt, int N,
                                                    int* __restrict__ partial) {
  __shared__ int sd[256];
  int i = blockIdx.x * 256 + threadIdx.x;
  sd[threadIdx.x] = (i < N) ? cnt[i] : 0;
  __syncthreads();
  for (int o = 128; o > 0; o >>= 1) {
    if (threadIdx.x < o) sd[threadIdx.x] += sd[threadIdx.x + o];
    __syncthreads();
  }
  if (threadIdx.x == 0) partial[blockIdx.x] = sd[0];
}

__global__ __launch_bounds__(256) void scanB_kernel(const int* __restrict__ partial, int nb,
                                                    int* __restrict__ blockoff) {
  __shared__ int sd[256];
  int t = threadIdx.x;
  int v = (t < nb) ? partial[t] : 0;
  sd[t] = v;
  __syncthreads();
  for (int o = 1; o < 256; o <<= 1) {
    int x = (t >= o) ? sd[t - o] : 0;
    __syncthreads();
    sd[t] += x;
    __syncthreads();
  }
  blockoff[t] = sd[t] - v;  // exclusive
}

__global__ __launch_bounds__(256) void scanC_kernel(
    const int* __restrict__ cnt, int N, const int* __restrict__ blockoff,
    int* __restrict__ off, int* __restrict__ cur, int E) {
  __shared__ int sd[256];
  int t = threadIdx.x;
  int i = blockIdx.x * 256 + t;
  int v = (i < N) ? cnt[i] : 0;
  sd[t] = v;
  __syncthreads();
  for (int o = 1; o < 256; o <<= 1) {
    int x = (t >= o) ? sd[t - o] : 0;
    __syncthreads();
    sd[t] += x;
    __syncthreads();
  }
  if (i < N) {
    int ex = blockoff[blockIdx.x] + sd[t] - v;
    off[i] = ex;
    cur[i] = ex;
  }
  if (i == 0) off[N] = E;
}

__global__ __launch_bounds__(256) void place_kernel(
    const int* __restrict__ row, const int* __restrict__ col, int E,
    int* __restrict__ cur, int* __restrict__ csr_src, int* __restrict__ csr_eid) {
  int e = blockIdx.x * 256 + threadIdx.x;
  if (e < E) {
    int slot = atomicAdd(&cur[col[e]], 1);
    csr_src[slot] = row[e];
    csr_eid[slot] = e;
  }
}

__global__ __launch_bounds__(256) void rsqrt_kernel(const float* __restrict__ deg,
                                                    float* __restrict__ dinv, int N) {
  int v = blockIdx.x * 256 + threadIdx.x;
  if (v < N) dinv[v] = 1.0f / sqrtf(deg[v] + 1.0f);  // +1 = self loop
}

// ---------------- aggregation: out[v] = relu(sum_in t[src]*w + t[v]*dinv[v]^2 + b) ----------------
__global__ __launch_bounds__(256) void agg_kernel(
    const float* __restrict__ t, const int* __restrict__ csr_src,
    const int* __restrict__ csr_eid, const float* __restrict__ att,
    const int* __restrict__ off, const float* __restrict__ dinv,
    const float* __restrict__ bias, float* __restrict__ out, int N) {
  int v = blockIdx.x * 4 + (threadIdx.x >> 6);
  if (v >= N) return;
  int lane = threadIdx.x & 63;
  float dv = dinv[v];
  const float2* t2 = (const float2*)t;
  float2 self = t2[(size_t)v * 64 + lane];
  float w0 = dv * dv;
  float ax = self.x * w0, ay = self.y * w0;
  int s0 = off[v], s1 = off[v + 1];
  if (att) {
    for (int s = s0; s < s1; ++s) {
      int src = csr_src[s];
      float w = dinv[src] * dv * att[csr_eid[s]];
      float2 m = t2[(size_t)src * 64 + lane];
      ax += m.x * w; ay += m.y * w;
    }
  } else {
    for (int s = s0; s < s1; ++s) {
      int src = csr_src[s];
      float w = dinv[src] * dv;
      float2 m = t2[(size_t)src * 64 + lane];
      ax += m.x * w; ay += m.y * w;
    }
  }
  float2 o;
  o.x = fmaxf(ax + bias[lane * 2], 0.f);
  o.y = fmaxf(ay + bias[lane * 2 + 1], 0.f);
  ((float2*)out)[(size_t)v * 64 + lane] = o;
}

// ---------------- node attention + p,q factors ----------------
__global__ __launch_bounds__(256) void natt_kernel(
    const float* __restrict__ h, int N,
    const float* __restrict__ W_na, const float* __restrict__ b_na,
    const float* __restrict__ W_ea,
    float* __restrict__ na0, float* __restrict__ na1,
    float* __restrict__ p0, float* __restrict__ p1,
    float* __restrict__ q0, float* __restrict__ q1) {
  int n = blockIdx.x * 256 + threadIdx.x;
  if (n >= N) return;
  float sa0 = 0, sa1 = 0, sp0 = 0, sp1 = 0, sq0 = 0, sq1 = 0;
  const float* hr = h + (size_t)n * H;
  for (int k = 0; k < H; k++) {
    float v = hr[k];
    sa0 += v * W_na[k * 2];       sa1 += v * W_na[k * 2 + 1];
    sp0 += v * W_ea[k * 2];       sp1 += v * W_ea[k * 2 + 1];
    sq0 += v * W_ea[(H + k) * 2]; sq1 += v * W_ea[(H + k) * 2 + 1];
  }
  sa0 += b_na[0]; sa1 += b_na[1];
  float m = fmaxf(sa0, sa1);
  float e0 = expf(sa0 - m), e1 = expf(sa1 - m);
  float inv = 1.f / (e0 + e1);
  na0[n] = e0 * inv; na1[n] = e1 * inv;
  p0[n] = sp0; p1[n] = sp1; q0[n] = sq0; q1[n] = sq1;
}

// ---------------- xc_pre = na0*h, xo_pre = na1*h ----------------
__global__ __launch_bounds__(256) void xpre_kernel(
    const float* __restrict__ h, const float* __restrict__ na0,
    const float* __restrict__ na1, float* __restrict__ xc,
    float* __restrict__ xo, int N) {
  int i = blockIdx.x * 256 + threadIdx.x;  // over N*32 float4s
  if (i >= N * 32) return;
  int n = i >> 5;
  float4 v = ((const float4*)h)[i];
  float a = na0[n], b = na1[n];
  float4 oc = {v.x * a, v.y * a, v.z * a, v.w * a};
  float4 oo = {v.x * b, v.y * b, v.z * b, v.w * b};
  ((float4*)xc)[i] = oc;
  ((float4*)xo)[i] = oo;
}

// ---------------- edge attention + weighted degree ----------------
__global__ __launch_bounds__(256) void eatt_kernel(
    const int* __restrict__ row, const int* __restrict__ col, int E,
    const float* __restrict__ p0, const float* __restrict__ p1,
    const float* __restrict__ q0, const float* __restrict__ q1,
    const float* __restrict__ b_ea,
    float* __restrict__ att0, float* __restrict__ att1,
    float* __restrict__ degc, float* __restrict__ dego) {
  int e = blockIdx.x * 256 + threadIdx.x;
  if (e >= E) return;
  int r = row[e], c = col[e];
  float l0 = p0[r] + q0[c] + b_ea[0];
  float l1 = p1[r] + q1[c] + b_ea[1];
  float m = fmaxf(l0, l1);
  float e0 = expf(l0 - m), e1 = expf(l1 - m);
  float inv = 1.f / (e0 + e1);
  float a0 = e0 * inv, a1 = e1 * inv;
  att0[e] = a0; att1[e] = a1;
  atomicAdd(&degc[r], a0);
  atomicAdd(&dego[r], a1);
}

// ---------------- h_co = xc[perm] + xo ----------------
__global__ __launch_bounds__(256) void permadd_kernel(
    const float* __restrict__ xc, const float* __restrict__ xo,
    const int* __restrict__ perm, float* __restrict__ out, int N) {
  int i = blockIdx.x * 256 + threadIdx.x;  // N*32 float4s
  if (i >= N * 32) return;
  int n = i >> 5, k = i & 31;
  int p = perm[n];
  float4 a = ((const float4*)xc)[(size_t)p * 32 + k];
  float4 b = ((const float4*)xo)[i];
  float4 o = {a.x + b.x, a.y + b.y, a.z + b.z, a.w + b.w};
  ((float4*)out)[i] = o;
}

// ---------------- fc2 [N,128]@[128,10] + log_softmax ----------------
__global__ __launch_bounds__(256) void fc2_kernel(
    const float* __restrict__ z, const float* __restrict__ W2,
    const float* __restrict__ c2, float* __restrict__ outp, int N) {
  int n = blockIdx.x * 256 + threadIdx.x;
  if (n >= N) return;
  float acc[NCLS];
#pragma unroll
  for (int c = 0; c < NCLS; c++) acc[c] = c2[c];
  const float* zr = z + (size_t)n * H;
  for (int k = 0; k < H; k++) {
    float v = zr[k];
#pragma unroll
    for (int c = 0; c < NCLS; c++) acc[c] += v * W2[k * NCLS + c];
  }
  float m = acc[0];
#pragma unroll
  for (int c = 1; c < NCLS; c++) m = fmaxf(m, acc[c]);
  float s = 0.f;
#pragma unroll
  for (int c = 0; c < NCLS; c++) s += expf(acc[c] - m);
  float lse = logf(s) + m;
#pragma unroll
  for (int c = 0; c < NCLS; c++) outp[(size_t)n * NCLS + c] = acc[c] - lse;
}

// =============================================================================
extern "C" void kernel_launch(void* const* d_in, const int* in_sizes, int n_in,
                              void* d_out, int out_size, void* d_ws, size_t ws_size,
                              hipStream_t stream) {
  const int N = in_sizes[0] / H;   // 50000
  const int E = in_sizes[1] / 2;   // 800000
  const float* x = (const float*)d_in[0];
  const int* ei = (const int*)d_in[1];
  const int* row = ei;
  const int* col = ei + E;
  const int* perm = (const int*)d_in[2];
  const float* W_feat = (const float*)d_in[3];
  const float* b_feat = (const float*)d_in[4];
  const float* W_convs = (const float*)d_in[5];
  const float* b_convs = (const float*)d_in[6];
  const float* W_ea = (const float*)d_in[7];
  const float* b_ea = (const float*)d_in[8];
  const float* W_na = (const float*)d_in[9];
  const float* b_na = (const float*)d_in[10];
  const float* W_ctx = (const float*)d_in[11];
  const float* b_ctx = (const float*)d_in[12];
  const float* W_obj = (const float*)d_in[13];
  const float* b_obj = (const float*)d_in[14];
  const float* W_fc1 = (const float*)d_in[15];
  const float* b_fc1 = (const float*)d_in[16];
  const float* W_fc2 = (const float*)d_in[17];
  const float* b_fc2 = (const float*)d_in[18];
  float* out = (float*)d_out;

  // ---------- workspace layout ----------
  float* ws = (float*)d_ws;
  size_t NB = (size_t)N * H;
  float* bufA = ws;            // h, later xo
  float* bufB = ws + NB;       // xc_pre -> xc
  float* bufC = ws + 2 * NB;   // t / xo_pre / z
  float* bufD = ws + 3 * NB;   // t_c,t_o / h_co
  float* misc = ws + 4 * NB;
  int* cnt = (int*)misc;                  // N
  float* deg = misc + N;                  // N   (zeroed with cnt..dego)
  float* degc = misc + 2 * (size_t)N;
  float* dego = misc + 3 * (size_t)N;
  int* off = (int*)(misc + 4 * (size_t)N);      // N+1
  int* cur = (int*)(misc + 5 * (size_t)N + 1);  // N
  float* dinv = misc + 6 * (size_t)N + 2;
  float* dinvc = misc + 7 * (size_t)N + 2;
  float* dinvo = misc + 8 * (size_t)N + 2;
  float* na0 = misc + 9 * (size_t)N + 2;
  float* na1 = misc + 10 * (size_t)N + 2;
  float* p0 = misc + 11 * (size_t)N + 2;
  float* p1 = misc + 12 * (size_t)N + 2;
  float* q0 = misc + 13 * (size_t)N + 2;
  float* q1 = misc + 14 * (size_t)N + 2;
  int* partial = (int*)(misc + 15 * (size_t)N + 2);  // 256
  int* blockoff = partial + 256;                     // 256
  float* colsum = (float*)(blockoff + 256);          // 128
  float* colsumsq = colsum + H;                      // 128
  float* Wf = colsumsq + H;                          // 128*128 (also reused as [128][10])
  float* cf = Wf + H * H;                            // 128
  float* att0 = cf + H;                              // E
  float* att1 = att0 + E;                            // E
  int* csr_src = (int*)(att1 + E);                   // E
  int* csr_eid = csr_src + E;                        // E

  const float invN = 1.0f / (float)N;
  const int gN = (N + 255) / 256;
  const int gE = (E + 255) / 256;
  const int SB = (N + 255) / 256;  // scan blocks (<=256)
  const int gG = (N + BM - 1) / BM;
  const int gV = (N * 32 + 255) / 256;  // float4 elementwise grids
  const int gAgg = (N + 3) / 4;

  // ---------- CSR + degrees (once per call) ----------
  hipMemsetAsync(cnt, 0, 4 * (size_t)N * sizeof(int), stream);  // cnt,deg,degc,dego
  hist_kernel<<<gE, 256, 0, stream>>>(row, col, E, cnt, deg);
  scanA_kernel<<<SB, 256, 0, stream>>>(cnt, N, partial);
  scanB_kernel<<<1, 256, 0, stream>>>(partial, SB, blockoff);
  scanC_kernel<<<SB, 256, 0, stream>>>(cnt, N, blockoff, off, cur, E);
  place_kernel<<<gE, 256, 0, stream>>>(row, col, E, cur, csr_src, csr_eid);
  rsqrt_kernel<<<gN, 256, 0, stream>>>(deg, dinv, N);

#define STATS(SRC)                                                        \
  hipMemsetAsync(colsum, 0, 2 * H * sizeof(float), stream);               \
  colstats_kernel<<<256, 256, 0, stream>>>((SRC), N, colsum, colsumsq);

  // ---------- feature layer: h = relu(bn(x)@W_feat + b_feat) ----------
  STATS(x);
  fold_kernel<<<H, H, 0, stream>>>(W_feat, b_feat, colsum, colsumsq, invN, H, Wf, cf);
  gemm_kernel<<<gG, 256, 0, stream>>>(x, Wf, cf, bufA, N, 1);

  // ---------- 3 GCN convs ----------
  for (int i = 0; i < 3; ++i) {
    STATS(bufA);
    fold_kernel<<<H, H, 0, stream>>>(W_convs + (size_t)i * H * H, nullptr, colsum,
                                     colsumsq, invN, H, Wf, cf);
    gemm_kernel<<<gG, 256, 0, stream>>>(bufA, Wf, cf, bufC, N, 0);
    agg_kernel<<<gAgg, 256, 0, stream>>>(bufC, csr_src, csr_eid, nullptr, off, dinv,
                                         b_convs + (size_t)i * H, bufA, N);
  }

  // ---------- attention ----------
  natt_kernel<<<gN, 256, 0, stream>>>(bufA, N, W_na, b_na, W_ea, na0, na1, p0, p1, q0, q1);
  eatt_kernel<<<gE, 256, 0, stream>>>(row, col, E, p0, p1, q0, q1, b_ea, att0, att1,
                                      degc, dego);
  rsqrt_kernel<<<gN, 256, 0, stream>>>(degc, dinvc, N);
  rsqrt_kernel<<<gN, 256, 0, stream>>>(dego, dinvo, N);
  xpre_kernel<<<gV, 256, 0, stream>>>(bufA, na0, na1, bufB, bufC, N);  // B=xc_pre C=xo_pre

  // ---------- ctx conv: xc = relu(gcn(bn(xc_pre), W_ctx, att0)) ----------
  STATS(bufB);
  fold_kernel<<<H, H, 0, stream>>>(W_ctx, nullptr, colsum, colsumsq, invN, H, Wf, cf);
  gemm_kernel<<<gG, 256, 0, stream>>>(bufB, Wf, cf, bufD, N, 0);
  agg_kernel<<<gAgg, 256, 0, stream>>>(bufD, csr_src, csr_eid, att0, off, dinvc, b_ctx,
                                       bufB, N);  // xc in B

  // ---------- obj conv: xo = relu(gcn(bn(xo_pre), W_obj, att1)) ----------
  STATS(bufC);
  fold_kernel<<<H, H, 0, stream>>>(W_obj, nullptr, colsum, colsumsq, invN, H, Wf, cf);
  gemm_kernel<<<gG, 256, 0, stream>>>(bufC, Wf, cf, bufD, N, 0);
  agg_kernel<<<gAgg, 256, 0, stream>>>(bufD, csr_src, csr_eid, att1, off, dinvo, b_obj,
                                       bufA, N);  // xo in A (h dead)

  // ---------- h_co = xc[perm] + xo ----------
  permadd_kernel<<<gV, 256, 0, stream>>>(bufB, bufA, perm, bufD, N);  // h_co in D

  // ---------- 3 readouts ----------
  const float* Xin[3] = {bufB, bufA, bufD};  // xc, xo, xco
  for (int j = 0; j < 3; ++j) {
    STATS(Xin[j]);
    fold_kernel<<<H, H, 0, stream>>>(W_fc1 + (size_t)j * H * H, b_fc1 + (size_t)j * H,
                                     colsum, colsumsq, invN, H, Wf, cf);
    gemm_kernel<<<gG, 256, 0, stream>>>(Xin[j], Wf, cf, bufC, N, 1);  // z=relu(bn(X)@W1+b1)
    STATS(bufC);
    fold_kernel<<<NCLS, H, 0, stream>>>(W_fc2 + (size_t)j * H * NCLS,
                                        b_fc2 + (size_t)j * NCLS, colsum, colsumsq,
                                        invN, NCLS, Wf, cf);
    fc2_kernel<<<gN, 256, 0, stream>>>(bufC, Wf, cf, out + (size_t)j * N * NCLS, N);
  }
#undef STATS
}

// Round 2
// 1424.577 us; speedup vs baseline: 1.1278x; 1.1278x over previous
//
#include <hip/hip_runtime.h>
#include <math.h>

#define H 128
#define NCLS 10
#define EPS 1e-5f
#define BN_BETA 1e-4f

typedef unsigned short u16;
typedef unsigned int u32;
typedef __attribute__((ext_vector_type(8))) short short8;
typedef __attribute__((ext_vector_type(4))) float floatx4;

// ---- bf16 helpers (bit ops; RNE) ----
__device__ inline float bflo(u32 u) { union { u32 i; float f; } a; a.i = u << 16; return a.f; }
__device__ inline float bfhi(u32 u) { union { u32 i; float f; } a; a.i = u & 0xffff0000u; return a.f; }
__device__ inline u16 f2bf(float f) {
  union { float f; u32 i; } v; v.f = f;
  return (u16)((v.i + 0x7fff + ((v.i >> 16) & 1)) >> 16);
}
__device__ inline u32 pack2(float a, float b) { return (u32)f2bf(a) | ((u32)f2bf(b) << 16); }

// ---------------- x fp32 -> bf16 ----------------
__global__ __launch_bounds__(256) void xcvt_kernel(const float* __restrict__ x,
                                                   u16* __restrict__ xb, int n4) {
  int i = blockIdx.x * 256 + threadIdx.x;  // over N*32 float4 chunks
  if (i >= n4) return;
  float4 v = ((const float4*)x)[i];
  u32 lo = pack2(v.x, v.y), hi = pack2(v.z, v.w);
  ((uint2*)xb)[i] = make_uint2(lo, hi);
}

// ---------------- column stats over bf16 [N,128] ----------------
__global__ __launch_bounds__(256) void colstats_kernel(
    const u16* __restrict__ X, int N, float* __restrict__ sum, float* __restrict__ sumsq) {
  int c2 = threadIdx.x & 63;   // col pair
  int sub = threadIdx.x >> 6;  // 0..3
  float s0 = 0, s1 = 0, q0 = 0, q1 = 0;
  const u32* X2 = (const u32*)X;
  for (int r = blockIdx.x * 4 + sub; r < N; r += gridDim.x * 4) {
    u32 u = X2[(size_t)r * 64 + c2];
    float a = bflo(u), b = bfhi(u);
    s0 += a; q0 += a * a; s1 += b; q1 += b * b;
  }
  __shared__ float4 red[256];
  red[threadIdx.x] = make_float4(s0, s1, q0, q1);
  __syncthreads();
  if (sub == 0) {
    float4 t1 = red[64 + c2], t2 = red[128 + c2], t3 = red[192 + c2];
    s0 += t1.x + t2.x + t3.x; s1 += t1.y + t2.y + t3.y;
    q0 += t1.z + t2.z + t3.z; q1 += t1.w + t2.w + t3.w;
    atomicAdd(&sum[2 * c2], s0); atomicAdd(&sum[2 * c2 + 1], s1);
    atomicAdd(&sumsq[2 * c2], q0); atomicAdd(&sumsq[2 * c2 + 1], q1);
  }
}

// ---------------- fold BN into W: Wt_bf[k][f]=s_f*W[f][k] (bf16, transposed), c[k] fp32
__global__ __launch_bounds__(128) void fold_kernel(
    const float* __restrict__ W, const float* __restrict__ bias,
    const float* __restrict__ sum, const float* __restrict__ sumsq, float invN,
    u16* __restrict__ Wt_bf, float* __restrict__ cout_) {
  int k = blockIdx.x;   // 0..127 output col
  int f = threadIdx.x;  // 0..127 input feature
  float mu = sum[f] * invN;
  float var = sumsq[f] * invN - mu * mu;
  float s = 1.0f / sqrtf(fmaxf(var, 0.f) + EPS);
  float w = W[(size_t)f * H + k];
  Wt_bf[(size_t)k * H + f] = f2bf(s * w);
  __shared__ float red[H];
  red[f] = (BN_BETA - mu * s) * w;
  __syncthreads();
  for (int o = 64; o > 0; o >>= 1) {
    if (f < o) red[f] += red[f + o];
    __syncthreads();
  }
  if (f == 0) cout_[k] = red[0] + (bias ? bias[k] : 0.f);
}

// ---------------- fold for fc2 (Kout=10), fp32 out ----------------
__global__ __launch_bounds__(128) void fold10_kernel(
    const float* __restrict__ W, const float* __restrict__ bias,
    const float* __restrict__ sum, const float* __restrict__ sumsq, float invN,
    float* __restrict__ Wout, float* __restrict__ cout_) {
  int k = blockIdx.x;   // 0..9
  int f = threadIdx.x;
  float mu = sum[f] * invN;
  float var = sumsq[f] * invN - mu * mu;
  float s = 1.0f / sqrtf(fmaxf(var, 0.f) + EPS);
  float w = W[(size_t)f * NCLS + k];
  Wout[(size_t)f * NCLS + k] = s * w;
  __shared__ float red[H];
  red[f] = (BN_BETA - mu * s) * w;
  __syncthreads();
  for (int o = 64; o > 0; o >>= 1) {
    if (f < o) red[f] += red[f + o];
    __syncthreads();
  }
  if (f == 0) cout_[k] = red[0] + bias[k];
}

// ---------------- bf16 MFMA GEMM: C[N,128] = A[N,128] @ Wf + c ----------------
// Bt is folded W transposed: Bt[n][k], bf16. One wave = 16 rows x 128 cols.
__global__ __launch_bounds__(256) void gemm_kernel(
    const u16* __restrict__ A, const u16* __restrict__ Bt,
    const float* __restrict__ bias, u16* __restrict__ C, int N, int relu) {
  int tid = threadIdx.x;
  int wave = tid >> 6, lane = tid & 63;
  int l15 = lane & 15, quad = lane >> 4;
  int row0 = (blockIdx.x * 4 + wave) * 16;
  if (row0 >= N) return;
  int arow = row0 + l15;
  short8 a[4];
  short8 z8 = {0, 0, 0, 0, 0, 0, 0, 0};
#pragma unroll
  for (int k4 = 0; k4 < 4; k4++)
    a[k4] = (arow < N) ? *(const short8*)(A + (size_t)arow * H + k4 * 32 + quad * 8) : z8;
#pragma unroll
  for (int nt = 0; nt < 8; nt++) {
    floatx4 acc = {0.f, 0.f, 0.f, 0.f};
    const u16* bp = Bt + (size_t)(nt * 16 + l15) * H + quad * 8;
#pragma unroll
    for (int k4 = 0; k4 < 4; k4++) {
      short8 b = *(const short8*)(bp + k4 * 32);
      acc = __builtin_amdgcn_mfma_f32_16x16x32_bf16(a[k4], b, acc, 0, 0, 0);
    }
    int col = nt * 16 + l15;
    float bs = bias[col];
#pragma unroll
    for (int r = 0; r < 4; r++) {
      int row = row0 + quad * 4 + r;
      if (row < N) {
        float v = acc[r] + bs;
        if (relu) v = fmaxf(v, 0.f);
        C[(size_t)row * H + col] = f2bf(v);
      }
    }
  }
}

// ---------------- CSR build ----------------
__global__ __launch_bounds__(256) void hist_kernel(
    const int* __restrict__ row, const int* __restrict__ col, int E,
    int* __restrict__ cnt, float* __restrict__ deg) {
  int e = blockIdx.x * 256 + threadIdx.x;
  if (e < E) {
    atomicAdd(&cnt[col[e]], 1);
    atomicAdd(&deg[row[e]], 1.0f);
  }
}

__global__ __launch_bounds__(256) void scanA_kernel(const int* __restrict__ cnt, int N,
                                                    int* __restrict__ partial) {
  __shared__ int sd[256];
  int i = blockIdx.x * 256 + threadIdx.x;
  sd[threadIdx.x] = (i < N) ? cnt[i] : 0;
  __syncthreads();
  for (int o = 128; o > 0; o >>= 1) {
    if (threadIdx.x < o) sd[threadIdx.x] += sd[threadIdx.x + o];
    __syncthreads();
  }
  if (threadIdx.x == 0) partial[blockIdx.x] = sd[0];
}

__global__ __launch_bounds__(256) void scanB_kernel(const int* __restrict__ partial, int nb,
                                                    int* __restrict__ blockoff) {
  __shared__ int sd[256];
  int t = threadIdx.x;
  int v = (t < nb) ? partial[t] : 0;
  sd[t] = v;
  __syncthreads();
  for (int o = 1; o < 256; o <<= 1) {
    int x = (t >= o) ? sd[t - o] : 0;
    __syncthreads();
    sd[t] += x;
    __syncthreads();
  }
  blockoff[t] = sd[t] - v;  // exclusive
}

__global__ __launch_bounds__(256) void scanC_kernel(
    const int* __restrict__ cnt, int N, const int* __restrict__ blockoff,
    int* __restrict__ off, int* __restrict__ cur, int E) {
  __shared__ int sd[256];
  int t = threadIdx.x;
  int i = blockIdx.x * 256 + t;
  int v = (i < N) ? cnt[i] : 0;
  sd[t] = v;
  __syncthreads();
  for (int o = 1; o < 256; o <<= 1) {
    int x = (t >= o) ? sd[t - o] : 0;
    __syncthreads();
    sd[t] += x;
    __syncthreads();
  }
  if (i < N) {
    int ex = blockoff[blockIdx.x] + sd[t] - v;
    off[i] = ex;
    cur[i] = ex;
  }
  if (i == 0) off[N] = E;
}

__global__ __launch_bounds__(256) void place_kernel(
    const int* __restrict__ row, const int* __restrict__ col, int E,
    int* __restrict__ cur, int* __restrict__ csr_src, int* __restrict__ csr_eid) {
  int e = blockIdx.x * 256 + threadIdx.x;
  if (e < E) {
    int slot = atomicAdd(&cur[col[e]], 1);
    csr_src[slot] = row[e];
    csr_eid[slot] = e;
  }
}

__global__ __launch_bounds__(256) void rsqrt_kernel(const float* __restrict__ deg,
                                                    float* __restrict__ dinv, int N) {
  int v = blockIdx.x * 256 + threadIdx.x;
  if (v < N) dinv[v] = 1.0f / sqrtf(deg[v] + 1.0f);  // +1 = self loop
}

// ---------------- aggregation (bf16 messages, fp32 accumulate) ----------------
__global__ __launch_bounds__(256) void agg_kernel(
    const u16* __restrict__ t, const int* __restrict__ csr_src,
    const int* __restrict__ csr_eid, const float* __restrict__ att,
    const int* __restrict__ off, const float* __restrict__ dinv,
    const float* __restrict__ bias, u16* __restrict__ out, int N) {
  int v = blockIdx.x * 4 + (threadIdx.x >> 6);
  if (v >= N) return;
  int lane = threadIdx.x & 63;
  float dv = dinv[v];
  const u32* t2 = (const u32*)t;
  u32 su = t2[(size_t)v * 64 + lane];
  float w0 = dv * dv;
  float ax = bflo(su) * w0, ay = bfhi(su) * w0;
  int s0 = off[v], s1 = off[v + 1];
  if (att) {
    for (int s = s0; s < s1; ++s) {
      int src = csr_src[s];
      float w = dinv[src] * dv * att[csr_eid[s]];
      u32 m = t2[(size_t)src * 64 + lane];
      ax += bflo(m) * w; ay += bfhi(m) * w;
    }
  } else {
    for (int s = s0; s < s1; ++s) {
      int src = csr_src[s];
      float w = dinv[src] * dv;
      u32 m = t2[(size_t)src * 64 + lane];
      ax += bflo(m) * w; ay += bfhi(m) * w;
    }
  }
  float ox = fmaxf(ax + bias[lane * 2], 0.f);
  float oy = fmaxf(ay + bias[lane * 2 + 1], 0.f);
  ((u32*)out)[(size_t)v * 64 + lane] = pack2(ox, oy);
}

// ---------------- node attention + edge-att p,q factors (h bf16) ----------------
__global__ __launch_bounds__(256) void natt_kernel(
    const u16* __restrict__ h, int N,
    const float* __restrict__ W_na, const float* __restrict__ b_na,
    const float* __restrict__ W_ea,
    float* __restrict__ na0, float* __restrict__ na1,
    float* __restrict__ p0, float* __restrict__ p1,
    float* __restrict__ q0, float* __restrict__ q1) {
  int n = blockIdx.x * 256 + threadIdx.x;
  if (n >= N) return;
  float sa0 = 0, sa1 = 0, sp0 = 0, sp1 = 0, sq0 = 0, sq1 = 0;
  const uint2* hr = (const uint2*)(h + (size_t)n * H);
  for (int c = 0; c < 32; c++) {  // 4 bf16 per iter
    uint2 u = hr[c];
    float v0 = bflo(u.x), v1 = bfhi(u.x), v2 = bflo(u.y), v3 = bfhi(u.y);
    int k = c * 4;
    sa0 += v0 * W_na[k * 2] + v1 * W_na[k * 2 + 2] + v2 * W_na[k * 2 + 4] + v3 * W_na[k * 2 + 6];
    sa1 += v0 * W_na[k * 2 + 1] + v1 * W_na[k * 2 + 3] + v2 * W_na[k * 2 + 5] + v3 * W_na[k * 2 + 7];
    sp0 += v0 * W_ea[k * 2] + v1 * W_ea[k * 2 + 2] + v2 * W_ea[k * 2 + 4] + v3 * W_ea[k * 2 + 6];
    sp1 += v0 * W_ea[k * 2 + 1] + v1 * W_ea[k * 2 + 3] + v2 * W_ea[k * 2 + 5] + v3 * W_ea[k * 2 + 7];
    sq0 += v0 * W_ea[(H + k) * 2] + v1 * W_ea[(H + k) * 2 + 2] + v2 * W_ea[(H + k) * 2 + 4] + v3 * W_ea[(H + k) * 2 + 6];
    sq1 += v0 * W_ea[(H + k) * 2 + 1] + v1 * W_ea[(H + k) * 2 + 3] + v2 * W_ea[(H + k) * 2 + 5] + v3 * W_ea[(H + k) * 2 + 7];
  }
  sa0 += b_na[0]; sa1 += b_na[1];
  float m = fmaxf(sa0, sa1);
  float e0 = expf(sa0 - m), e1 = expf(sa1 - m);
  float inv = 1.f / (e0 + e1);
  na0[n] = e0 * inv; na1[n] = e1 * inv;
  p0[n] = sp0; p1[n] = sp1; q0[n] = sq0; q1[n] = sq1;
}

// ---------------- xc_pre = na0*h, xo_pre = na1*h (bf16) ----------------
__global__ __launch_bounds__(256) void xpre_kernel(
    const u16* __restrict__ h, const float* __restrict__ na0,
    const float* __restrict__ na1, u16* __restrict__ xc, u16* __restrict__ xo, int n4) {
  int i = blockIdx.x * 256 + threadIdx.x;  // over N*32 4-elem chunks
  if (i >= n4) return;
  int n = i >> 5;
  uint2 u = ((const uint2*)h)[i];
  float v0 = bflo(u.x), v1 = bfhi(u.x), v2 = bflo(u.y), v3 = bfhi(u.y);
  float a = na0[n], b = na1[n];
  ((uint2*)xc)[i] = make_uint2(pack2(v0 * a, v1 * a), pack2(v2 * a, v3 * a));
  ((uint2*)xo)[i] = make_uint2(pack2(v0 * b, v1 * b), pack2(v2 * b, v3 * b));
}

// ---------------- edge attention + weighted degree ----------------
__global__ __launch_bounds__(256) void eatt_kernel(
    const int* __restrict__ row, const int* __restrict__ col, int E,
    const float* __restrict__ p0, const float* __restrict__ p1,
    const float* __restrict__ q0, const float* __restrict__ q1,
    const float* __restrict__ b_ea,
    float* __restrict__ att0, float* __restrict__ att1,
    float* __restrict__ degc, float* __restrict__ dego) {
  int e = blockIdx.x * 256 + threadIdx.x;
  if (e >= E) return;
  int r = row[e], c = col[e];
  float l0 = p0[r] + q0[c] + b_ea[0];
  float l1 = p1[r] + q1[c] + b_ea[1];
  float m = fmaxf(l0, l1);
  float e0 = expf(l0 - m), e1 = expf(l1 - m);
  float inv = 1.f / (e0 + e1);
  float a0 = e0 * inv, a1 = e1 * inv;
  att0[e] = a0; att1[e] = a1;
  atomicAdd(&degc[r], a0);
  atomicAdd(&dego[r], a1);
}

// ---------------- h_co = xc[perm] + xo (bf16) ----------------
__global__ __launch_bounds__(256) void permadd_kernel(
    const u16* __restrict__ xc, const u16* __restrict__ xo,
    const int* __restrict__ perm, u16* __restrict__ out, int n4) {
  int i = blockIdx.x * 256 + threadIdx.x;
  if (i >= n4) return;
  int n = i >> 5, k = i & 31;
  int p = perm[n];
  uint2 a = ((const uint2*)xc)[(size_t)p * 32 + k];
  uint2 b = ((const uint2*)xo)[i];
  ((uint2*)out)[i] = make_uint2(pack2(bflo(a.x) + bflo(b.x), bfhi(a.x) + bfhi(b.x)),
                                pack2(bflo(a.y) + bflo(b.y), bfhi(a.y) + bfhi(b.y)));
}

// ---------------- fc2 [N,128]@[128,10] + log_softmax (z bf16) ----------------
__global__ __launch_bounds__(256) void fc2_kernel(
    const u16* __restrict__ z, const float* __restrict__ W2,
    const float* __restrict__ c2, float* __restrict__ outp, int N) {
  int n = blockIdx.x * 256 + threadIdx.x;
  if (n >= N) return;
  float acc[NCLS];
#pragma unroll
  for (int c = 0; c < NCLS; c++) acc[c] = c2[c];
  const uint2* zr = (const uint2*)(z + (size_t)n * H);
  for (int c4 = 0; c4 < 32; c4++) {
    uint2 u = zr[c4];
    float v[4] = {bflo(u.x), bfhi(u.x), bflo(u.y), bfhi(u.y)};
    int k = c4 * 4;
#pragma unroll
    for (int j = 0; j < 4; j++)
#pragma unroll
      for (int c = 0; c < NCLS; c++) acc[c] += v[j] * W2[(k + j) * NCLS + c];
  }
  float m = acc[0];
#pragma unroll
  for (int c = 1; c < NCLS; c++) m = fmaxf(m, acc[c]);
  float s = 0.f;
#pragma unroll
  for (int c = 0; c < NCLS; c++) s += expf(acc[c] - m);
  float lse = logf(s) + m;
#pragma unroll
  for (int c = 0; c < NCLS; c++) outp[(size_t)n * NCLS + c] = acc[c] - lse;
}

// =============================================================================
extern "C" void kernel_launch(void* const* d_in, const int* in_sizes, int n_in,
                              void* d_out, int out_size, void* d_ws, size_t ws_size,
                              hipStream_t stream) {
  const int N = in_sizes[0] / H;   // 50000
  const int E = in_sizes[1] / 2;   // 800000
  const float* x = (const float*)d_in[0];
  const int* ei = (const int*)d_in[1];
  const int* row = ei;
  const int* col = ei + E;
  const int* perm = (const int*)d_in[2];
  const float* W_feat = (const float*)d_in[3];
  const float* b_feat = (const float*)d_in[4];
  const float* W_convs = (const float*)d_in[5];
  const float* b_convs = (const float*)d_in[6];
  const float* W_ea = (const float*)d_in[7];
  const float* b_ea = (const float*)d_in[8];
  const float* W_na = (const float*)d_in[9];
  const float* b_na = (const float*)d_in[10];
  const float* W_ctx = (const float*)d_in[11];
  const float* b_ctx = (const float*)d_in[12];
  const float* W_obj = (const float*)d_in[13];
  const float* b_obj = (const float*)d_in[14];
  const float* W_fc1 = (const float*)d_in[15];
  const float* b_fc1 = (const float*)d_in[16];
  const float* W_fc2 = (const float*)d_in[17];
  const float* b_fc2 = (const float*)d_in[18];
  float* out = (float*)d_out;

  // ---------- workspace carve (256 B aligned) ----------
  char* base = (char*)d_ws;
  size_t off_b = 0;
  auto alloc = [&](size_t bytes) -> void* {
    void* p = base + off_b;
    off_b = (off_b + bytes + 255) & ~(size_t)255;
    return p;
  };
  size_t NB2 = (size_t)N * H * sizeof(u16);
  u16* bufA = (u16*)alloc(NB2);  // h, later xo
  u16* bufB = (u16*)alloc(NB2);  // xc_pre -> xc
  u16* bufC = (u16*)alloc(NB2);  // t / xo_pre / z
  u16* bufD = (u16*)alloc(NB2);  // t_c,t_o / h_co
  u16* xbf = (u16*)alloc(NB2);   // x in bf16
  int* cnt = (int*)alloc(4 * (size_t)N * 4);  // cnt,deg,degc,dego contiguous (one memset)
  float* deg = (float*)(cnt + N);
  float* degc = (float*)(cnt + 2 * (size_t)N);
  float* dego = (float*)(cnt + 3 * (size_t)N);
  int* off = (int*)alloc(((size_t)N + 1) * 4);
  int* cur = (int*)alloc((size_t)N * 4);
  float* dinv = (float*)alloc((size_t)N * 4);
  float* dinvc = (float*)alloc((size_t)N * 4);
  float* dinvo = (float*)alloc((size_t)N * 4);
  float* na0 = (float*)alloc((size_t)N * 4);
  float* na1 = (float*)alloc((size_t)N * 4);
  float* p0 = (float*)alloc((size_t)N * 4);
  float* p1 = (float*)alloc((size_t)N * 4);
  float* q0 = (float*)alloc((size_t)N * 4);
  float* q1 = (float*)alloc((size_t)N * 4);
  int* partial = (int*)alloc(256 * 4);
  int* blockoff = (int*)alloc(256 * 4);
  float* colsum = (float*)alloc(2 * H * 4);  // colsum+colsumsq contiguous (one memset)
  float* colsumsq = colsum + H;
  u16* Wt = (u16*)alloc((size_t)H * H * 2);   // folded W, transposed, bf16
  float* cf = (float*)alloc(H * 4);
  float* W2f = (float*)alloc((size_t)H * NCLS * 4);
  float* c2f = (float*)alloc(16 * 4);
  float* att0 = (float*)alloc((size_t)E * 4);
  float* att1 = (float*)alloc((size_t)E * 4);
  int* csr_src = (int*)alloc((size_t)E * 4);
  int* csr_eid = (int*)alloc((size_t)E * 4);

  const float invN = 1.0f / (float)N;
  const int gN = (N + 255) / 256;
  const int gE = (E + 255) / 256;
  const int SB = (N + 255) / 256;
  const int gG = (N + 63) / 64;          // gemm: 4 waves x 16 rows per block
  const int n4 = N * 32;                 // 4-elem chunks
  const int gV = (n4 + 255) / 256;
  const int gAgg = (N + 3) / 4;

  // ---------- CSR + degrees ----------
  hipMemsetAsync(cnt, 0, 4 * (size_t)N * sizeof(int), stream);
  hist_kernel<<<gE, 256, 0, stream>>>(row, col, E, cnt, deg);
  scanA_kernel<<<SB, 256, 0, stream>>>(cnt, N, partial);
  scanB_kernel<<<1, 256, 0, stream>>>(partial, SB, blockoff);
  scanC_kernel<<<SB, 256, 0, stream>>>(cnt, N, blockoff, off, cur, E);
  place_kernel<<<gE, 256, 0, stream>>>(row, col, E, cur, csr_src, csr_eid);
  rsqrt_kernel<<<gN, 256, 0, stream>>>(deg, dinv, N);

#define STATS(SRC)                                                  \
  hipMemsetAsync(colsum, 0, 2 * H * sizeof(float), stream);         \
  colstats_kernel<<<256, 256, 0, stream>>>((SRC), N, colsum, colsumsq);

  // ---------- feature layer ----------
  xcvt_kernel<<<gV, 256, 0, stream>>>(x, xbf, n4);
  STATS(xbf);
  fold_kernel<<<H, H, 0, stream>>>(W_feat, b_feat, colsum, colsumsq, invN, Wt, cf);
  gemm_kernel<<<gG, 256, 0, stream>>>(xbf, Wt, cf, bufA, N, 1);

  // ---------- 3 GCN convs ----------
  for (int i = 0; i < 3; ++i) {
    STATS(bufA);
    fold_kernel<<<H, H, 0, stream>>>(W_convs + (size_t)i * H * H, nullptr, colsum,
                                     colsumsq, invN, Wt, cf);
    gemm_kernel<<<gG, 256, 0, stream>>>(bufA, Wt, cf, bufC, N, 0);
    agg_kernel<<<gAgg, 256, 0, stream>>>(bufC, csr_src, csr_eid, nullptr, off, dinv,
                                         b_convs + (size_t)i * H, bufA, N);
  }

  // ---------- attention ----------
  natt_kernel<<<gN, 256, 0, stream>>>(bufA, N, W_na, b_na, W_ea, na0, na1, p0, p1, q0, q1);
  eatt_kernel<<<gE, 256, 0, stream>>>(row, col, E, p0, p1, q0, q1, b_ea, att0, att1,
                                      degc, dego);
  rsqrt_kernel<<<gN, 256, 0, stream>>>(degc, dinvc, N);
  rsqrt_kernel<<<gN, 256, 0, stream>>>(dego, dinvo, N);
  xpre_kernel<<<gV, 256, 0, stream>>>(bufA, na0, na1, bufB, bufC, n4);  // B=xc_pre C=xo_pre

  // ---------- ctx conv ----------
  STATS(bufB);
  fold_kernel<<<H, H, 0, stream>>>(W_ctx, nullptr, colsum, colsumsq, invN, Wt, cf);
  gemm_kernel<<<gG, 256, 0, stream>>>(bufB, Wt, cf, bufD, N, 0);
  agg_kernel<<<gAgg, 256, 0, stream>>>(bufD, csr_src, csr_eid, att0, off, dinvc, b_ctx,
                                       bufB, N);  // xc in B

  // ---------- obj conv ----------
  STATS(bufC);
  fold_kernel<<<H, H, 0, stream>>>(W_obj, nullptr, colsum, colsumsq, invN, Wt, cf);
  gemm_kernel<<<gG, 256, 0, stream>>>(bufC, Wt, cf, bufD, N, 0);
  agg_kernel<<<gAgg, 256, 0, stream>>>(bufD, csr_src, csr_eid, att1, off, dinvo, b_obj,
                                       bufA, N);  // xo in A

  // ---------- h_co = xc[perm] + xo ----------
  permadd_kernel<<<gV, 256, 0, stream>>>(bufB, bufA, perm, bufD, n4);

  // ---------- 3 readouts ----------
  const u16* Xin[3] = {bufB, bufA, bufD};  // xc, xo, xco
  for (int j = 0; j < 3; ++j) {
    STATS(Xin[j]);
    fold_kernel<<<H, H, 0, stream>>>(W_fc1 + (size_t)j * H * H, b_fc1 + (size_t)j * H,
                                     colsum, colsumsq, invN, Wt, cf);
    gemm_kernel<<<gG, 256, 0, stream>>>(Xin[j], Wt, cf, bufC, N, 1);
    STATS(bufC);
    fold10_kernel<<<NCLS, H, 0, stream>>>(W_fc2 + (size_t)j * H * NCLS,
                                          b_fc2 + (size_t)j * NCLS, colsum, colsumsq,
                                          invN, W2f, c2f);
    fc2_kernel<<<gN, 256, 0, stream>>>(bufC, W2f, c2f, out + (size_t)j * N * NCLS, N);
  }
#undef STATS
}